// Round 13
// baseline (245.857 us; speedup 1.0000x reference)
//
#include <hip/hip_runtime.h>

// ---------------- constants (B=8,S=8192 -> N=65536, D=512, E=209) ------------
#define DK 512
#define NSTEP 16            // K steps of 32
#define NPANEL 14           // expert panels of 16 -> EPAD
#define EPAD 224
#define LP 225              // logits row stride (f32), phase 2
#define WF_ELEMS (EPAD * DK)        // 114688 fp16
#define STEPB 14336         // bytes per (step x 14 panels) fp16 frag block

typedef __attribute__((ext_vector_type(8))) _Float16 f16x8;  // 16 B = 4 VGPR
typedef __attribute__((ext_vector_type(4))) float f32x4;

// async global->LDS, 16 B per lane; LDS dest wave-uniform (+lane*16 implicit),
// global src per-lane.
__device__ __forceinline__ void gld16(const void* g, void* l) {
    __builtin_amdgcn_global_load_lds(
        (const __attribute__((address_space(1))) unsigned int*)g,
        (__attribute__((address_space(3))) unsigned int*)l, 16, 0, 0);
}

// ---------------------------------------------------------------- init -------
extern "C" __global__ void moe_init(float* hist, float* probsum, int* cnt) {
    int t = threadIdx.x;
    if (t < EPAD) { hist[t] = 0.f; probsum[t] = 0.f; }
    if (t == 0) *cnt = 0;
}

// ---------------------------------------------------------------- prep -------
// w [E][DK] f32 -> fragment-major fp16 (RNE). Chunk (kk*14+p) at byte
// (kk*14+p)*1024; lane l at +l*16 holds w[p*16+(l&15)][kk*32+(l>>4)*8 + j].
extern "C" __global__ void __launch_bounds__(256)
moe_prep(const float* __restrict__ w, _Float16* __restrict__ wF, int E)
{
    int g = blockIdx.x * 256 + threadIdx.x;      // 0..14335
    int l  = g & 63;
    int pc = g >> 6;
    int kk = pc / NPANEL;
    int p  = pc - kk * NPANEL;
    int e  = p * 16 + (l & 15);
    int k0 = kk * 32 + (l >> 4) * 8;
    float4 v0 = make_float4(0.f,0.f,0.f,0.f), v1 = v0;
    if (e < E) {
        v0 = *(const float4*)(w + (size_t)e * DK + k0);
        v1 = *(const float4*)(w + (size_t)e * DK + k0 + 4);
    }
    f16x8 h;
    h[0] = (_Float16)v0.x; h[1] = (_Float16)v0.y;
    h[2] = (_Float16)v0.z; h[3] = (_Float16)v0.w;
    h[4] = (_Float16)v1.x; h[5] = (_Float16)v1.y;
    h[6] = (_Float16)v1.z; h[7] = (_Float16)v1.w;
    *(f16x8*)(wF + (size_t)g * 8) = h;
}

// ---------------------------------------------------------------- copy -------
// Standalone coalesced x -> out copy (x_flat), stores kept out of the GEMM.
extern "C" __global__ void __launch_bounds__(256)
moe_copy(const float4* __restrict__ xin, float4* __restrict__ outv, int n4)
{
    int i = blockIdx.x * 256 + threadIdx.x;
    int stride = gridDim.x * 256;
    for (; i < n4; i += stride) outv[i] = xin[i];
}

// ---------------------------------------------------------------- gemm -------
// Single-term FP16 MFMA GEMM. 4 waves: wm = token half (32 tok), wn = panel
// half (7 panels of 16 experts). Rolled 2-step parity K loop; B staged per
// step (14 KB) via global_load_lds double-buffer; A direct global->reg + cvt.
// LDS ~29 KB -> 4+ blocks/CU (16 waves/CU TLP).
extern "C" __global__ void __launch_bounds__(256, 4)
moe_gemm(const float* __restrict__ x,
         const _Float16* __restrict__ wF,
         float* __restrict__ out,
         float* __restrict__ hist,
         float* __restrict__ probsum_g,
         int* __restrict__ flag_cnt,
         int* __restrict__ flag_list,
         int flag_cap, int N, int E)
{
    __shared__ float sbuf[32 * LP];              // 28.8 KB; B dbuf aliases it
    __shared__ float ps_l[EPAD];
    __shared__ float tok_m[32], tok_s[32];
    char* Bl0 = (char*)sbuf;                     // 14336 B
    char* Bl1 = (char*)sbuf + STEPB;             // 14336 B (total 28672 <= 28800)

    const int t    = threadIdx.x;
    const int l    = t & 63;
    const int wid  = t >> 6;
    const int wm   = wid >> 1;                   // token half
    const int wn   = wid & 1;                    // panel half
    const int le   = l & 15;
    const int lg   = l >> 4;
    const int tok0 = blockIdx.x * 64;
    const char* wFb = (const char*)wF;

    if (t < EPAD) ps_l[t] = 0.f;

    f32x4 acc[2][7];
    #pragma unroll
    for (int mi = 0; mi < 2; ++mi)
        #pragma unroll
        for (int j = 0; j < 7; ++j)
            acc[mi][j] = (f32x4){0.f, 0.f, 0.f, 0.f};

    float4 A0[2][2], A1[2][2];                   // named parity regs (rule #20)

    // stage step kk's 14 KB B block: wave wid covers chunks wid*4 .. wid*4+3
    #define STAGE_B(kk_, buf_)                                                  \
        {   _Pragma("unroll")                                                   \
            for (int i_ = 0; i_ < 4; ++i_) {                                    \
                int c_ = wid * 4 + i_;                                          \
                if (c_ < NPANEL)                                                \
                    gld16(wFb + (size_t)(kk_) * STEPB + c_ * 1024 + l * 16,     \
                          (buf_) + c_ * 1024);                                  \
            }                                                                   \
        }
    #define LOAD_A(dst_, kk_)                                                   \
        {   _Pragma("unroll")                                                   \
            for (int mi_ = 0; mi_ < 2; ++mi_) {                                 \
                const float* ar_ = x + (size_t)(tok0 + wm * 32 + mi_ * 16 + le) * DK \
                                 + (kk_) * 32 + lg * 8;                         \
                dst_[mi_][0] = *(const float4*)ar_;                             \
                dst_[mi_][1] = *(const float4*)(ar_ + 4);                       \
            }                                                                   \
        }
    #define COMPUTE(Asrc_, Bbase_)                                              \
        {   f16x8 af_[2];                                                       \
            _Pragma("unroll")                                                   \
            for (int mi_ = 0; mi_ < 2; ++mi_) {                                 \
                float vv_[8] = {Asrc_[mi_][0].x, Asrc_[mi_][0].y,               \
                                Asrc_[mi_][0].z, Asrc_[mi_][0].w,               \
                                Asrc_[mi_][1].x, Asrc_[mi_][1].y,               \
                                Asrc_[mi_][1].z, Asrc_[mi_][1].w};              \
                _Pragma("unroll")                                               \
                for (int j_ = 0; j_ < 8; ++j_) af_[mi_][j_] = (_Float16)vv_[j_]; \
            }                                                                   \
            _Pragma("unroll")                                                   \
            for (int j_ = 0; j_ < 7; ++j_) {                                    \
                int q_ = wn * 7 + j_;                                           \
                f16x8 bf_ = *(const f16x8*)((Bbase_) + q_ * 1024 + l * 16);     \
                _Pragma("unroll")                                               \
                for (int mi_ = 0; mi_ < 2; ++mi_)                               \
                    acc[mi_][j_] = __builtin_amdgcn_mfma_f32_16x16x32_f16(      \
                        af_[mi_], bf_, acc[mi_][j_], 0, 0, 0);                  \
            }                                                                   \
        }

    // prologue
    LOAD_A(A0, 0);
    STAGE_B(0, Bl0);
    __syncthreads();

    #pragma unroll 1
    for (int kb = 0; kb < NSTEP / 2; ++kb) {
        const int e = 2 * kb;
        LOAD_A(A1, e + 1);                       // e+1 <= 15 always
        STAGE_B(e + 1, Bl1);
        COMPUTE(A0, Bl0);
        __syncthreads();                         // Bl0 reads done; stage(e+1) landed
        const int o = e + 1;
        if (o + 1 < NSTEP) {                     // uniform branch
            LOAD_A(A0, o + 1);
            STAGE_B(o + 1, Bl0);
        }
        COMPUTE(A1, Bl1);
        __syncthreads();
    }
    #undef LOAD_A
    #undef COMPUTE
    #undef STAGE_B

    // -------- phase 2: two 32-token passes over LDS logits (R5-verified) ----
    float* logits = sbuf;

    for (int pass = 0; pass < 2; ++pass) {
        __syncthreads();
        if (wm == pass) {
            #pragma unroll
            for (int mi = 0; mi < 2; ++mi)
                #pragma unroll
                for (int nj = 0; nj < 7; ++nj)
                    #pragma unroll
                    for (int rg = 0; rg < 4; ++rg) {
                        int rr = mi * 16 + (l >> 4) * 4 + rg;   // 0..31
                        int cc = wn * 112 + nj * 16 + (l & 15); // 0..223
                        logits[rr * LP + cc] = acc[mi][nj][rg];
                    }
        }
        __syncthreads();
        {   // 8 threads per token: top-2 + softmax denom
            int r = t >> 3, sub = t & 7;
            float m1 = -1e30f, m2 = -1e30f;
            int i1 = 0x7fffffff;
            for (int e = sub; e < E; e += 8) {
                float v = logits[r * LP + e];
                if (v > m1) { m2 = m1; m1 = v; i1 = e; }
                else if (v > m2) { m2 = v; }
            }
            #pragma unroll
            for (int mask = 1; mask < 8; mask <<= 1) {
                float om1 = __shfl_xor(m1, mask);
                float om2 = __shfl_xor(m2, mask);
                int   oi1 = __shfl_xor(i1, mask);
                if (om1 > m1 || (om1 == m1 && oi1 < i1)) {
                    m2 = fmaxf(m1, om2); m1 = om1; i1 = oi1;
                } else {
                    m2 = fmaxf(m2, om1);
                }
            }
            float s = 0.f;
            for (int e = sub; e < E; e += 8) s += __expf(logits[r * LP + e] - m1);
            #pragma unroll
            for (int mask = 1; mask < 8; mask <<= 1) s += __shfl_xor(s, mask);

            if (sub == 0) {
                float sinv = 1.0f / s;
                tok_m[r] = m1; tok_s[r] = sinv;
                int tok = tok0 + pass * 32 + r;
                out[(size_t)N * DK + tok]     = sinv;        // max prob
                out[(size_t)N * DK + N + tok] = (float)i1;   // expert index
                atomicAdd(&hist[i1], 1.0f);
                if (m1 - m2 < 1e-3f) {                       // fp16-ambiguous argmax
                    int pos = atomicAdd(flag_cnt, 1);
                    if (pos < flag_cap) flag_list[pos] = tok;
                }
            }
        }
        __syncthreads();
        if (t < E) {                             // thread = expert: no atomics
            float sum = 0.f;
            #pragma unroll 4
            for (int r = 0; r < 32; ++r)
                sum += __expf(logits[r * LP + t] - tok_m[r]) * tok_s[r];
            ps_l[t] += sum;
        }
    }
    __syncthreads();
    if (t < E) atomicAdd(&probsum_g[t], ps_l[t]);
}

// ------------------------------------------------------------- refine --------
// f64 recompute (original f32 w) for tokens with fp16 top-2 gap < tau.
extern "C" __global__ void __launch_bounds__(256)
moe_refine(const float* __restrict__ x,
           const float* __restrict__ w,
           float* __restrict__ hist,
           const int* __restrict__ flag_cnt,
           const int* __restrict__ flag_list,
           int flag_cap,
           float* __restrict__ out,
           int N, int E)
{
    __shared__ float  xsh[DK];
    __shared__ double rv[256];
    __shared__ int    ri[256];
    int nf = *flag_cnt; if (nf > flag_cap) nf = flag_cap;
    const int tid = threadIdx.x;

    for (int li = blockIdx.x; li < nf; li += gridDim.x) {
        int tok = flag_list[li];
        for (int k = tid; k < DK; k += 256) xsh[k] = x[(size_t)tok * DK + k];
        __syncthreads();
        double a = -1e300;
        if (tid < E) {
            const float* wr = w + (size_t)tid * DK;
            double a0 = 0, a1 = 0, a2 = 0, a3 = 0;
            for (int k = 0; k < DK; k += 4) {
                a0 += (double)xsh[k]     * (double)wr[k];
                a1 += (double)xsh[k + 1] * (double)wr[k + 1];
                a2 += (double)xsh[k + 2] * (double)wr[k + 2];
                a3 += (double)xsh[k + 3] * (double)wr[k + 3];
            }
            a = (a0 + a1) + (a2 + a3);
        }
        rv[tid] = a; ri[tid] = tid;
        __syncthreads();
        for (int s = 128; s > 0; s >>= 1) {
            if (tid < s) {
                double vb = rv[tid + s]; int ib = ri[tid + s];
                double va = rv[tid];     int ia = ri[tid];
                if (vb > va || (vb == va && ib < ia)) { rv[tid] = vb; ri[tid] = ib; }
            }
            __syncthreads();
        }
        if (tid == 0) {
            int newi = ri[0];
            int oldi = (int)out[(size_t)N * DK + N + tok];
            if (newi != oldi) {
                atomicAdd(&hist[oldi], -1.0f);
                atomicAdd(&hist[newi],  1.0f);
                out[(size_t)N * DK + N + tok] = (float)newi;
            }
        }
        __syncthreads();
    }
}

// ------------------------------------------------------------ finalize -------
extern "C" __global__ void __launch_bounds__(256)
moe_final(const float* __restrict__ hist,
          const float* __restrict__ probsum,
          const float* __restrict__ ec_in,
          const float* __restrict__ gps_in,
          float* __restrict__ out,
          int N, int E)
{
    __shared__ double red[256];
    int t = threadIdx.x;
    double p = 0.0;
    if (t < E) p = (double)hist[t] * (double)probsum[t];
    red[t] = p;
    __syncthreads();
    for (int s = 128; s > 0; s >>= 1) {
        if (t < s) red[t] += red[t + s];
        __syncthreads();
    }
    size_t base = (size_t)N * DK + 2 * (size_t)N;
    if (t == 0) {
        double loss = (double)E * red[0] / ((double)N * (double)N);
        out[base] = (float)loss;
    }
    if (t < E) {
        out[base + 1 + t]     = 0.9f * ec_in[t]  + 0.1f * hist[t];
        out[base + 1 + E + t] = 0.9f * gps_in[t] + 0.1f * probsum[t];
    }
}

// ------------------------------------------------------------- launch --------
extern "C" void kernel_launch(void* const* d_in, const int* in_sizes, int n_in,
                              void* d_out, int out_size, void* d_ws, size_t ws_size,
                              hipStream_t stream)
{
    const float* x   = (const float*)d_in[0];
    const float* w   = (const float*)d_in[1];
    const float* ec  = (const float*)d_in[2];
    const float* gps = (const float*)d_in[3];
    float* out = (float*)d_out;

    int E = in_sizes[2];              // 209
    int N = in_sizes[0] / DK;         // 65536

    _Float16* wF   = (_Float16*)d_ws;
    float* hist    = (float*)(wF + WF_ELEMS);
    float* probsum = hist + EPAD;
    int*   cnt     = (int*)(probsum + EPAD);
    int*   list    = cnt + 1;
    long long used = 2LL * WF_ELEMS + 4LL * (2 * EPAD + 1);
    long long cap_ll = ((long long)ws_size - used) / 4;
    int cap = cap_ll < 0 ? 0 : (cap_ll > 65536 ? 65536 : (int)cap_ll);

    int n4 = (N * DK) / 4;

    moe_prep  <<<56,     256, 0, stream>>>(w, wF, E);
    moe_init  <<<1,      256, 0, stream>>>(hist, probsum, cnt);
    moe_gemm  <<<N / 64, 256, 0, stream>>>(x, wF, out, hist, probsum, cnt, list, cap, N, E);
    moe_copy  <<<2048,   256, 0, stream>>>((const float4*)x, (float4*)out, n4);
    moe_refine<<<256,    256, 0, stream>>>(x, w, hist, cnt, list, cap, out, N, E);
    moe_final <<<1,      256, 0, stream>>>(hist, probsum, ec, gps, out, N, E);
}

// Round 14
// 245.752 us; speedup vs baseline: 1.0004x; 1.0004x over previous
//
#include <hip/hip_runtime.h>

// ---------------- constants (B=8,S=8192 -> N=65536, D=512, E=209) ------------
#define DK 512
#define NSTEP 16            // K steps of 32
#define NPANEL 14           // expert panels of 16 -> EPAD
#define EPAD 224
#define LP 225              // logits row stride (f32), phase 2
#define WF_ELEMS (EPAD * DK)        // 114688 fp16
#define STEPB 14336         // bytes per (step x 14 panels) fp16 frag block

typedef __attribute__((ext_vector_type(8))) _Float16 f16x8;  // 16 B = 4 VGPR
typedef __attribute__((ext_vector_type(4))) float f32x4;

// async global->LDS, 16 B per lane; LDS dest wave-uniform (+lane*16 implicit),
// global src per-lane.
__device__ __forceinline__ void gld16(const void* g, void* l) {
    __builtin_amdgcn_global_load_lds(
        (const __attribute__((address_space(1))) unsigned int*)g,
        (__attribute__((address_space(3))) unsigned int*)l, 16, 0, 0);
}

// ---------------------------------------------------------------- init -------
extern "C" __global__ void moe_init(float* hist, float* probsum, int* cnt) {
    int t = threadIdx.x;
    if (t < EPAD) { hist[t] = 0.f; probsum[t] = 0.f; }
    if (t == 0) *cnt = 0;
}

// ---------------------------------------------------------------- prep -------
// w [E][DK] f32 -> fragment-major fp16 (RNE). Chunk (kk*14+p) at byte
// (kk*14+p)*1024; lane l at +l*16 holds w[p*16+(l&15)][kk*32+(l>>4)*8 + j].
extern "C" __global__ void __launch_bounds__(256)
moe_prep(const float* __restrict__ w, _Float16* __restrict__ wF, int E)
{
    int g = blockIdx.x * 256 + threadIdx.x;      // 0..14335
    int l  = g & 63;
    int pc = g >> 6;
    int kk = pc / NPANEL;
    int p  = pc - kk * NPANEL;
    int e  = p * 16 + (l & 15);
    int k0 = kk * 32 + (l >> 4) * 8;
    float4 v0 = make_float4(0.f,0.f,0.f,0.f), v1 = v0;
    if (e < E) {
        v0 = *(const float4*)(w + (size_t)e * DK + k0);
        v1 = *(const float4*)(w + (size_t)e * DK + k0 + 4);
    }
    f16x8 h;
    h[0] = (_Float16)v0.x; h[1] = (_Float16)v0.y;
    h[2] = (_Float16)v0.z; h[3] = (_Float16)v0.w;
    h[4] = (_Float16)v1.x; h[5] = (_Float16)v1.y;
    h[6] = (_Float16)v1.z; h[7] = (_Float16)v1.w;
    *(f16x8*)(wF + (size_t)g * 8) = h;
}

// ---------------------------------------------------------------- copy -------
// Runs BEFORE the GEMM: streams x HBM->L3 (warming it) while writing x_flat.
extern "C" __global__ void __launch_bounds__(256)
moe_copy(const float4* __restrict__ xin, float4* __restrict__ outv, int n4)
{
    int i = blockIdx.x * 256 + threadIdx.x;
    int stride = gridDim.x * 256;
    for (; i < n4; i += stride) outv[i] = xin[i];
}

// ---------------------------------------------------------------- gemm -------
// Single-term FP16 MFMA GEMM (R13 structure, x now L3-warm from moe_copy).
// 4 waves: wm = token half (32 tok), wn = panel half (7 panels of 16 experts).
// Rolled 2-step parity K loop; B staged per step (14 KB) via global_load_lds
// double-buffer; A direct global->reg + cvt.
extern "C" __global__ void __launch_bounds__(256, 4)
moe_gemm(const float* __restrict__ x,
         const _Float16* __restrict__ wF,
         float* __restrict__ out,
         float* __restrict__ hist,
         float* __restrict__ probsum_g,
         int* __restrict__ flag_cnt,
         int* __restrict__ flag_list,
         int flag_cap, int N, int E)
{
    __shared__ float sbuf[32 * LP];              // 28.8 KB; B dbuf aliases it
    __shared__ float ps_l[EPAD];
    __shared__ float tok_m[32], tok_s[32];
    char* Bl0 = (char*)sbuf;                     // 14336 B
    char* Bl1 = (char*)sbuf + STEPB;             // 14336 B

    const int t    = threadIdx.x;
    const int l    = t & 63;
    const int wid  = t >> 6;
    const int wm   = wid >> 1;                   // token half
    const int wn   = wid & 1;                    // panel half
    const int le   = l & 15;
    const int lg   = l >> 4;
    const int tok0 = blockIdx.x * 64;
    const char* wFb = (const char*)wF;

    if (t < EPAD) ps_l[t] = 0.f;

    f32x4 acc[2][7];
    #pragma unroll
    for (int mi = 0; mi < 2; ++mi)
        #pragma unroll
        for (int j = 0; j < 7; ++j)
            acc[mi][j] = (f32x4){0.f, 0.f, 0.f, 0.f};

    float4 A0[2][2], A1[2][2];                   // named parity regs (rule #20)

    #define STAGE_B(kk_, buf_)                                                  \
        {   _Pragma("unroll")                                                   \
            for (int i_ = 0; i_ < 4; ++i_) {                                    \
                int c_ = wid * 4 + i_;                                          \
                if (c_ < NPANEL)                                                \
                    gld16(wFb + (size_t)(kk_) * STEPB + c_ * 1024 + l * 16,     \
                          (buf_) + c_ * 1024);                                  \
            }                                                                   \
        }
    #define LOAD_A(dst_, kk_)                                                   \
        {   _Pragma("unroll")                                                   \
            for (int mi_ = 0; mi_ < 2; ++mi_) {                                 \
                const float* ar_ = x + (size_t)(tok0 + wm * 32 + mi_ * 16 + le) * DK \
                                 + (kk_) * 32 + lg * 8;                         \
                dst_[mi_][0] = *(const float4*)ar_;                             \
                dst_[mi_][1] = *(const float4*)(ar_ + 4);                       \
            }                                                                   \
        }
    #define COMPUTE(Asrc_, Bbase_)                                              \
        {   f16x8 af_[2];                                                       \
            _Pragma("unroll")                                                   \
            for (int mi_ = 0; mi_ < 2; ++mi_) {                                 \
                float vv_[8] = {Asrc_[mi_][0].x, Asrc_[mi_][0].y,               \
                                Asrc_[mi_][0].z, Asrc_[mi_][0].w,               \
                                Asrc_[mi_][1].x, Asrc_[mi_][1].y,               \
                                Asrc_[mi_][1].z, Asrc_[mi_][1].w};              \
                _Pragma("unroll")                                               \
                for (int j_ = 0; j_ < 8; ++j_) af_[mi_][j_] = (_Float16)vv_[j_]; \
            }                                                                   \
            _Pragma("unroll")                                                   \
            for (int j_ = 0; j_ < 7; ++j_) {                                    \
                int q_ = wn * 7 + j_;                                           \
                f16x8 bf_ = *(const f16x8*)((Bbase_) + q_ * 1024 + l * 16);     \
                _Pragma("unroll")                                               \
                for (int mi_ = 0; mi_ < 2; ++mi_)                               \
                    acc[mi_][j_] = __builtin_amdgcn_mfma_f32_16x16x32_f16(      \
                        af_[mi_], bf_, acc[mi_][j_], 0, 0, 0);                  \
            }                                                                   \
        }

    // prologue
    LOAD_A(A0, 0);
    STAGE_B(0, Bl0);
    __syncthreads();

    #pragma unroll 1
    for (int kb = 0; kb < NSTEP / 2; ++kb) {
        const int e = 2 * kb;
        LOAD_A(A1, e + 1);                       // e+1 <= 15 always
        STAGE_B(e + 1, Bl1);
        COMPUTE(A0, Bl0);
        __syncthreads();                         // Bl0 reads done; stage(e+1) landed
        const int o = e + 1;
        if (o + 1 < NSTEP) {                     // uniform branch
            LOAD_A(A0, o + 1);
            STAGE_B(o + 1, Bl0);
        }
        COMPUTE(A1, Bl1);
        __syncthreads();
    }
    #undef LOAD_A
    #undef COMPUTE
    #undef STAGE_B

    // -------- phase 2: two 32-token passes over LDS logits (R5-verified) ----
    float* logits = sbuf;

    for (int pass = 0; pass < 2; ++pass) {
        __syncthreads();
        if (wm == pass) {
            #pragma unroll
            for (int mi = 0; mi < 2; ++mi)
                #pragma unroll
                for (int nj = 0; nj < 7; ++nj)
                    #pragma unroll
                    for (int rg = 0; rg < 4; ++rg) {
                        int rr = mi * 16 + (l >> 4) * 4 + rg;   // 0..31
                        int cc = wn * 112 + nj * 16 + (l & 15); // 0..223
                        logits[rr * LP + cc] = acc[mi][nj][rg];
                    }
        }
        __syncthreads();
        {   // 8 threads per token: top-2 + softmax denom
            int r = t >> 3, sub = t & 7;
            float m1 = -1e30f, m2 = -1e30f;
            int i1 = 0x7fffffff;
            for (int e = sub; e < E; e += 8) {
                float v = logits[r * LP + e];
                if (v > m1) { m2 = m1; m1 = v; i1 = e; }
                else if (v > m2) { m2 = v; }
            }
            #pragma unroll
            for (int mask = 1; mask < 8; mask <<= 1) {
                float om1 = __shfl_xor(m1, mask);
                float om2 = __shfl_xor(m2, mask);
                int   oi1 = __shfl_xor(i1, mask);
                if (om1 > m1 || (om1 == m1 && oi1 < i1)) {
                    m2 = fmaxf(m1, om2); m1 = om1; i1 = oi1;
                } else {
                    m2 = fmaxf(m2, om1);
                }
            }
            float s = 0.f;
            for (int e = sub; e < E; e += 8) s += __expf(logits[r * LP + e] - m1);
            #pragma unroll
            for (int mask = 1; mask < 8; mask <<= 1) s += __shfl_xor(s, mask);

            if (sub == 0) {
                float sinv = 1.0f / s;
                tok_m[r] = m1; tok_s[r] = sinv;
                int tok = tok0 + pass * 32 + r;
                out[(size_t)N * DK + tok]     = sinv;        // max prob
                out[(size_t)N * DK + N + tok] = (float)i1;   // expert index
                atomicAdd(&hist[i1], 1.0f);
                if (m1 - m2 < 1e-3f) {                       // fp16-ambiguous argmax
                    int pos = atomicAdd(flag_cnt, 1);
                    if (pos < flag_cap) flag_list[pos] = tok;
                }
            }
        }
        __syncthreads();
        if (t < E) {                             // thread = expert: no atomics
            float sum = 0.f;
            #pragma unroll 4
            for (int r = 0; r < 32; ++r)
                sum += __expf(logits[r * LP + t] - tok_m[r]) * tok_s[r];
            ps_l[t] += sum;
        }
    }
    __syncthreads();
    if (t < E) atomicAdd(&probsum_g[t], ps_l[t]);
}

// ------------------------------------------------------------- refine --------
// f64 recompute (original f32 w) for tokens with fp16 top-2 gap < tau.
extern "C" __global__ void __launch_bounds__(256)
moe_refine(const float* __restrict__ x,
           const float* __restrict__ w,
           float* __restrict__ hist,
           const int* __restrict__ flag_cnt,
           const int* __restrict__ flag_list,
           int flag_cap,
           float* __restrict__ out,
           int N, int E)
{
    __shared__ float  xsh[DK];
    __shared__ double rv[256];
    __shared__ int    ri[256];
    int nf = *flag_cnt; if (nf > flag_cap) nf = flag_cap;
    const int tid = threadIdx.x;

    for (int li = blockIdx.x; li < nf; li += gridDim.x) {
        int tok = flag_list[li];
        for (int k = tid; k < DK; k += 256) xsh[k] = x[(size_t)tok * DK + k];
        __syncthreads();
        double a = -1e300;
        if (tid < E) {
            const float* wr = w + (size_t)tid * DK;
            double a0 = 0, a1 = 0, a2 = 0, a3 = 0;
            for (int k = 0; k < DK; k += 4) {
                a0 += (double)xsh[k]     * (double)wr[k];
                a1 += (double)xsh[k + 1] * (double)wr[k + 1];
                a2 += (double)xsh[k + 2] * (double)wr[k + 2];
                a3 += (double)xsh[k + 3] * (double)wr[k + 3];
            }
            a = (a0 + a1) + (a2 + a3);
        }
        rv[tid] = a; ri[tid] = tid;
        __syncthreads();
        for (int s = 128; s > 0; s >>= 1) {
            if (tid < s) {
                double vb = rv[tid + s]; int ib = ri[tid + s];
                double va = rv[tid];     int ia = ri[tid];
                if (vb > va || (vb == va && ib < ia)) { rv[tid] = vb; ri[tid] = ib; }
            }
            __syncthreads();
        }
        if (tid == 0) {
            int newi = ri[0];
            int oldi = (int)out[(size_t)N * DK + N + tok];
            if (newi != oldi) {
                atomicAdd(&hist[oldi], -1.0f);
                atomicAdd(&hist[newi],  1.0f);
                out[(size_t)N * DK + N + tok] = (float)newi;
            }
        }
        __syncthreads();
    }
}

// ------------------------------------------------------------ finalize -------
extern "C" __global__ void __launch_bounds__(256)
moe_final(const float* __restrict__ hist,
          const float* __restrict__ probsum,
          const float* __restrict__ ec_in,
          const float* __restrict__ gps_in,
          float* __restrict__ out,
          int N, int E)
{
    __shared__ double red[256];
    int t = threadIdx.x;
    double p = 0.0;
    if (t < E) p = (double)hist[t] * (double)probsum[t];
    red[t] = p;
    __syncthreads();
    for (int s = 128; s > 0; s >>= 1) {
        if (t < s) red[t] += red[t + s];
        __syncthreads();
    }
    size_t base = (size_t)N * DK + 2 * (size_t)N;
    if (t == 0) {
        double loss = (double)E * red[0] / ((double)N * (double)N);
        out[base] = (float)loss;
    }
    if (t < E) {
        out[base + 1 + t]     = 0.9f * ec_in[t]  + 0.1f * hist[t];
        out[base + 1 + E + t] = 0.9f * gps_in[t] + 0.1f * probsum[t];
    }
}

// ------------------------------------------------------------- launch --------
extern "C" void kernel_launch(void* const* d_in, const int* in_sizes, int n_in,
                              void* d_out, int out_size, void* d_ws, size_t ws_size,
                              hipStream_t stream)
{
    const float* x   = (const float*)d_in[0];
    const float* w   = (const float*)d_in[1];
    const float* ec  = (const float*)d_in[2];
    const float* gps = (const float*)d_in[3];
    float* out = (float*)d_out;

    int E = in_sizes[2];              // 209
    int N = in_sizes[0] / DK;         // 65536

    _Float16* wF   = (_Float16*)d_ws;
    float* hist    = (float*)(wF + WF_ELEMS);
    float* probsum = hist + EPAD;
    int*   cnt     = (int*)(probsum + EPAD);
    int*   list    = cnt + 1;
    long long used = 2LL * WF_ELEMS + 4LL * (2 * EPAD + 1);
    long long cap_ll = ((long long)ws_size - used) / 4;
    int cap = cap_ll < 0 ? 0 : (cap_ll > 65536 ? 65536 : (int)cap_ll);

    int n4 = (N * DK) / 4;

    moe_prep  <<<56,     256, 0, stream>>>(w, wF, E);
    moe_init  <<<1,      256, 0, stream>>>(hist, probsum, cnt);
    moe_copy  <<<4096,   256, 0, stream>>>((const float4*)x, (float4*)out, n4);  // warms x in L3
    moe_gemm  <<<N / 64, 256, 0, stream>>>(x, wF, out, hist, probsum, cnt, list, cap, N, E);
    moe_refine<<<256,    256, 0, stream>>>(x, w, hist, cnt, list, cap, out, N, E);
    moe_final <<<1,      256, 0, stream>>>(hist, probsum, ec, gps, out, N, E);
}